// Round 6
// baseline (74.707 us; speedup 1.0000x reference)
//
#include <hip/hip_runtime.h>

#define HH 4096
#define WW 4096
#define KK 256
#define RMAX 10
#define DD 21
#define NSQ (DD * DD)              // 441
#define MAXTOUCH (KK * NSQ)        // 112896

#define GRID 2048
#define TPB 256
#define STRIDE (GRID * TPB)        // float4 units = 524288

typedef float vfloat4 __attribute__((ext_vector_type(4)));

// d_ws layout (bytes):
#define FIX_OFF   0                      // double fix_delta[KK]      (2048 B)
#define PSF_OFF   4096                   // double part_sf[GRID]      (16384 B)
#define PSU_OFF   20480                  // double part_su[GRID]      (16384 B)
#define SCALE_OFF 36864                  // float  scale
#define LIDX_OFF  40960                  // int    list_idx[MAXTOUCH] (451584 B)
#define LFU_OFF   (40960 + 451584)       // float  list_fu[MAXTOUCH]

// K0: zero the 21x21 in-bounds square of every attractor in the addmap.
// addmap lives in d_out (stale output during replays; overwritten later).
__global__ void ecli_clear(const int* __restrict__ pos, float* __restrict__ addmap) {
    const int k = blockIdx.x;
    const int t = threadIdx.x;
    if (t >= NSQ) return;
    const int ni = pos[2 * k + 0] + t / DD - RMAX;
    const int nj = pos[2 * k + 1] + t % DD - RMAX;
    if (ni < 0 || ni >= HH || nj < 0 || nj >= WW) return;
    addmap[(size_t)ni * WW + nj] = 0.0f;
}

// K1: scatter-add attractor contributions (f32 atomics, uncontended).
__global__ void ecli_scatter(const int* __restrict__ pos,
                             const float* __restrict__ strength,
                             const float* __restrict__ local_ratio,
                             float* __restrict__ addmap) {
    const int k = blockIdx.x;
    const int t = threadIdx.x;
    if (t >= NSQ) return;
    const float s   = strength[k];
    const float lr  = *local_ratio;
    const float rad = floorf(5.0f * s);
    const float inv = -0.5f / (4.0f * s * s);
    const float amp = lr * s;
    const int di = t / DD - RMAX;
    const int dj = t % DD - RMAX;
    if (fabsf((float)di) > rad || fabsf((float)dj) > rad) return;
    const int ni = pos[2 * k + 0] + di;
    const int nj = pos[2 * k + 1] + dj;
    if (ni < 0 || ni >= HH || nj < 0 || nj >= WW) return;
    const float c = expf((float)(di * di + dj * dj) * inv) * amp;
    atomicAdd(&addmap[(size_t)ni * WW + nj], c);
}

// K2: claim each touched pixel once (atomicExch->0), write (idx, fu1) into
// deterministic slot, block-reduce the su-correction into fix_delta[k].
__global__ void ecli_fixup(const int* __restrict__ pos,
                           const float* __restrict__ field,
                           const float* __restrict__ signal,
                           const float* __restrict__ gratio,
                           const float* __restrict__ infl,
                           float* __restrict__ addmap,
                           int* __restrict__ list_idx,
                           float* __restrict__ list_fu,
                           double* __restrict__ fix_delta) {
    const int k = blockIdx.x;
    const int t = threadIdx.x;
    double delta = 0.0;
    if (t < NSQ) {
        int out_idx = -1;
        float out_fu = 0.0f;
        const int ni = pos[2 * k + 0] + t / DD - RMAX;
        const int nj = pos[2 * k + 1] + t % DD - RMAX;
        if (ni >= 0 && ni < HH && nj >= 0 && nj < WW) {
            const size_t idx = (size_t)ni * WW + nj;
            const float val = atomicExch(&addmap[idx], 0.0f);
            if (val != 0.0f) {
                const float gr = *gratio;
                const float is = *infl;
                const float f = field[idx];
                const float g = signal[idx];
                const float m0 = is / (1.0f + expf(-gr));
                const float m1 = is / (1.0f + expf(-(gr + val)));
                const float fu0 = fmaf(g - f, m0, f);
                const float fu1 = fmaf(g - f, m1, f);
                out_idx = (int)idx;
                out_fu  = fu1;
                delta = (double)fu1 * (double)fu1 - (double)fu0 * (double)fu0;
            }
        }
        list_idx[k * NSQ + t] = out_idx;
        list_fu [k * NSQ + t] = out_fu;
    }
    __shared__ double sred[7];
    #pragma unroll
    for (int off = 32; off > 0; off >>= 1) delta += __shfl_down(delta, off);
    if ((t & 63) == 0) sred[t >> 6] = delta;
    __syncthreads();
    if (t == 0) {
        double d = 0.0;
        #pragma unroll
        for (int i = 0; i < 7; ++i) d += sred[i];
        fix_delta[k] = d;
    }
}

// K3: norms only — read field+signal, f32 per-thread accumulation (32 terms),
// all 16 loads issued before any use. No 64MB store.
__global__ void __launch_bounds__(TPB) ecli_norms(
        const float* __restrict__ field,
        const float* __restrict__ signal,
        const float* __restrict__ gratio,
        const float* __restrict__ infl,
        double* __restrict__ part_sf,
        double* __restrict__ part_su) {
    const int tid = blockIdx.x * TPB + threadIdx.x;
    const float gr = *gratio;
    const float is = *infl;
    const float m0 = is / (1.0f + expf(-gr));
    const float4* __restrict__ F = (const float4*)field;
    const float4* __restrict__ G = (const float4*)signal;

    float4 f0 = F[tid + 0 * STRIDE], f1 = F[tid + 1 * STRIDE];
    float4 f2 = F[tid + 2 * STRIDE], f3 = F[tid + 3 * STRIDE];
    float4 f4 = F[tid + 4 * STRIDE], f5 = F[tid + 5 * STRIDE];
    float4 f6 = F[tid + 6 * STRIDE], f7 = F[tid + 7 * STRIDE];
    float4 g0 = G[tid + 0 * STRIDE], g1 = G[tid + 1 * STRIDE];
    float4 g2 = G[tid + 2 * STRIDE], g3 = G[tid + 3 * STRIDE];
    float4 g4 = G[tid + 4 * STRIDE], g5 = G[tid + 5 * STRIDE];
    float4 g6 = G[tid + 6 * STRIDE], g7 = G[tid + 7 * STRIDE];

    float sf = 0.0f, su = 0.0f;
    #define ACC4(f, g)                                                      \
    {                                                                       \
        float r;                                                            \
        sf += f.x*f.x + f.y*f.y + f.z*f.z + f.w*f.w;                        \
        r = fmaf(g.x - f.x, m0, f.x); su = fmaf(r, r, su);                  \
        r = fmaf(g.y - f.y, m0, f.y); su = fmaf(r, r, su);                  \
        r = fmaf(g.z - f.z, m0, f.z); su = fmaf(r, r, su);                  \
        r = fmaf(g.w - f.w, m0, f.w); su = fmaf(r, r, su);                  \
    }
    ACC4(f0, g0) ACC4(f1, g1) ACC4(f2, g2) ACC4(f3, g3)
    ACC4(f4, g4) ACC4(f5, g5) ACC4(f6, g6) ACC4(f7, g7)
    #undef ACC4

    double a = (double)sf, b = (double)su;
    __shared__ double sred[8];
    #pragma unroll
    for (int off = 32; off > 0; off >>= 1) {
        a += __shfl_down(a, off);
        b += __shfl_down(b, off);
    }
    if ((threadIdx.x & 63) == 0) {
        sred[(threadIdx.x >> 6) * 2 + 0] = a;
        sred[(threadIdx.x >> 6) * 2 + 1] = b;
    }
    __syncthreads();
    if (threadIdx.x == 0) {
        part_sf[blockIdx.x] = sred[0] + sred[2] + sred[4] + sred[6];
        part_su[blockIdx.x] = sred[1] + sred[3] + sred[5] + sred[7];
    }
}

// K4: single-block reduce of partials + fix corrections -> scale.
__global__ void ecli_reduce(const double* __restrict__ part_sf,
                            const double* __restrict__ part_su,
                            const double* __restrict__ fix_delta,
                            float* __restrict__ scale_out) {
    const int t = threadIdx.x;     // 1024 threads
    double a = 0.0, b = 0.0;
    for (int i = t; i < GRID; i += 1024) {
        a += part_sf[i];
        b += part_su[i];
    }
    if (t < KK) b += fix_delta[t];
    __shared__ double sa[16], sb[16];
    #pragma unroll
    for (int off = 32; off > 0; off >>= 1) {
        a += __shfl_down(a, off);
        b += __shfl_down(b, off);
    }
    if ((t & 63) == 0) { sa[t >> 6] = a; sb[t >> 6] = b; }
    __syncthreads();
    if (t == 0) {
        double ta = 0.0, tb = 0.0;
        #pragma unroll
        for (int i = 0; i < 16; ++i) { ta += sa[i]; tb += sb[i]; }
        *scale_out = (tb > 0.0) ? (float)sqrt(ta / tb) : 1.0f;
    }
}

// K5: write out = (f + (g-f)*m0) * scale, nontemporal stores, 16 loads batched.
__global__ void __launch_bounds__(TPB) ecli_write(
        const float* __restrict__ field,
        const float* __restrict__ signal,
        const float* __restrict__ gratio,
        const float* __restrict__ infl,
        const float* __restrict__ scale_ptr,
        float* __restrict__ out) {
    const int tid = blockIdx.x * TPB + threadIdx.x;
    const float gr = *gratio;
    const float is = *infl;
    const float m0 = is / (1.0f + expf(-gr));
    const float scale = *scale_ptr;
    const float4* __restrict__ F = (const float4*)field;
    const float4* __restrict__ G = (const float4*)signal;
    vfloat4* __restrict__ O = (vfloat4*)out;

    float4 f0 = F[tid + 0 * STRIDE], f1 = F[tid + 1 * STRIDE];
    float4 f2 = F[tid + 2 * STRIDE], f3 = F[tid + 3 * STRIDE];
    float4 f4 = F[tid + 4 * STRIDE], f5 = F[tid + 5 * STRIDE];
    float4 f6 = F[tid + 6 * STRIDE], f7 = F[tid + 7 * STRIDE];
    float4 g0 = G[tid + 0 * STRIDE], g1 = G[tid + 1 * STRIDE];
    float4 g2 = G[tid + 2 * STRIDE], g3 = G[tid + 3 * STRIDE];
    float4 g4 = G[tid + 4 * STRIDE], g5 = G[tid + 5 * STRIDE];
    float4 g6 = G[tid + 6 * STRIDE], g7 = G[tid + 7 * STRIDE];

    #define BLEND4(f, g, v)                                                 \
    {                                                                       \
        float t_;                                                           \
        t_ = fmaf(g.x - f.x, m0, f.x); v.x = t_ * scale;                    \
        t_ = fmaf(g.y - f.y, m0, f.y); v.y = t_ * scale;                    \
        t_ = fmaf(g.z - f.z, m0, f.z); v.z = t_ * scale;                    \
        t_ = fmaf(g.w - f.w, m0, f.w); v.w = t_ * scale;                    \
    }
    vfloat4 v;
    BLEND4(f0, g0, v) __builtin_nontemporal_store(v, &O[tid + 0 * STRIDE]);
    BLEND4(f1, g1, v) __builtin_nontemporal_store(v, &O[tid + 1 * STRIDE]);
    BLEND4(f2, g2, v) __builtin_nontemporal_store(v, &O[tid + 2 * STRIDE]);
    BLEND4(f3, g3, v) __builtin_nontemporal_store(v, &O[tid + 3 * STRIDE]);
    BLEND4(f4, g4, v) __builtin_nontemporal_store(v, &O[tid + 4 * STRIDE]);
    BLEND4(f5, g5, v) __builtin_nontemporal_store(v, &O[tid + 5 * STRIDE]);
    BLEND4(f6, g6, v) __builtin_nontemporal_store(v, &O[tid + 6 * STRIDE]);
    BLEND4(f7, g7, v) __builtin_nontemporal_store(v, &O[tid + 7 * STRIDE]);
    #undef BLEND4
}

// K6: apply sparse corrections, scaled.
__global__ void ecli_apply(const int* __restrict__ list_idx,
                           const float* __restrict__ list_fu,
                           const float* __restrict__ scale_ptr,
                           float* __restrict__ out) {
    const int tid = blockIdx.x * blockDim.x + threadIdx.x;
    if (tid >= MAXTOUCH) return;
    const int idx = list_idx[tid];
    if (idx < 0) return;
    out[idx] = list_fu[tid] * (*scale_ptr);
}

extern "C" void kernel_launch(void* const* d_in, const int* in_sizes, int n_in,
                              void* d_out, int out_size, void* d_ws, size_t ws_size,
                              hipStream_t stream) {
    const float* field    = (const float*)d_in[0];
    const float* signal   = (const float*)d_in[1];
    const int*   pos      = (const int*)d_in[2];
    const float* strength = (const float*)d_in[3];
    const float* infl     = (const float*)d_in[4];
    const float* gratio   = (const float*)d_in[5];
    const float* lratio   = (const float*)d_in[6];
    float* out = (float*)d_out;

    char* ws = (char*)d_ws;
    double* fix_delta = (double*)(ws + FIX_OFF);
    double* part_sf   = (double*)(ws + PSF_OFF);
    double* part_su   = (double*)(ws + PSU_OFF);
    float*  scale_ptr = (float*)(ws + SCALE_OFF);
    int*    list_idx  = (int*)(ws + LIDX_OFF);
    float*  list_fu   = (float*)(ws + LFU_OFF);

    ecli_clear  <<<KK, 448, 0, stream>>>(pos, out);
    ecli_scatter<<<KK, 448, 0, stream>>>(pos, strength, lratio, out);
    ecli_fixup  <<<KK, 448, 0, stream>>>(pos, field, signal, gratio, infl,
                                         out, list_idx, list_fu, fix_delta);
    ecli_norms  <<<GRID, TPB, 0, stream>>>(field, signal, gratio, infl,
                                           part_sf, part_su);
    ecli_reduce <<<1, 1024, 0, stream>>>(part_sf, part_su, fix_delta, scale_ptr);
    ecli_write  <<<GRID, TPB, 0, stream>>>(field, signal, gratio, infl,
                                           scale_ptr, out);
    ecli_apply  <<<(MAXTOUCH + 255) / 256, 256, 0, stream>>>(list_idx, list_fu,
                                                             scale_ptr, out);
}

// Round 7
// 73.592 us; speedup vs baseline: 1.0151x; 1.0151x over previous
//
#include <hip/hip_runtime.h>

#define HH 4096
#define WW 4096
#define KK 256
#define RMAX 10
#define DD 21
#define NSQ (DD * DD)              // 441
#define MAXTOUCH (KK * NSQ)        // 112896

#define NB  8192                   // blocks for dense kernels
#define TPB 256
#define NT  (NB * TPB)             // 2097152 threads; 2 float4 each

typedef float vfloat4 __attribute__((ext_vector_type(4)));

// d_ws layout (bytes):
#define FIX_OFF   0                      // double fix_delta[KK]      (2048 B)
#define PSF_OFF   4096                   // double part_sf[NB]        (65536 B)
#define PSU_OFF   (4096 + 65536)         // double part_su[NB]        (65536 B)
#define SCALE_OFF (4096 + 2 * 65536)     // float  scale
#define LIDX_OFF  (SCALE_OFF + 4096)     // int    list_idx[MAXTOUCH]
#define LFU_OFF   (LIDX_OFF + 451584)    // float  list_fu[MAXTOUCH]

// K0: zero the 21x21 in-bounds square of every attractor in the addmap.
// addmap lives in d_out (stale output during replays; overwritten later).
__global__ void ecli_clear(const int* __restrict__ pos, float* __restrict__ addmap) {
    const int k = blockIdx.x;
    const int t = threadIdx.x;
    if (t >= NSQ) return;
    const int ni = pos[2 * k + 0] + t / DD - RMAX;
    const int nj = pos[2 * k + 1] + t % DD - RMAX;
    if (ni < 0 || ni >= HH || nj < 0 || nj >= WW) return;
    addmap[(size_t)ni * WW + nj] = 0.0f;
}

// K1: scatter-add attractor contributions (f32 atomics, uncontended).
__global__ void ecli_scatter(const int* __restrict__ pos,
                             const float* __restrict__ strength,
                             const float* __restrict__ local_ratio,
                             float* __restrict__ addmap) {
    const int k = blockIdx.x;
    const int t = threadIdx.x;
    if (t >= NSQ) return;
    const float s   = strength[k];
    const float lr  = *local_ratio;
    const float rad = floorf(5.0f * s);
    const float inv = -0.5f / (4.0f * s * s);
    const float amp = lr * s;
    const int di = t / DD - RMAX;
    const int dj = t % DD - RMAX;
    if (fabsf((float)di) > rad || fabsf((float)dj) > rad) return;
    const int ni = pos[2 * k + 0] + di;
    const int nj = pos[2 * k + 1] + dj;
    if (ni < 0 || ni >= HH || nj < 0 || nj >= WW) return;
    const float c = expf((float)(di * di + dj * dj) * inv) * amp;
    atomicAdd(&addmap[(size_t)ni * WW + nj], c);
}

// K2: claim each touched pixel once (atomicExch->0), write (idx, fu1) into
// deterministic slot, block-reduce the su-correction into fix_delta[k].
__global__ void ecli_fixup(const int* __restrict__ pos,
                           const float* __restrict__ field,
                           const float* __restrict__ signal,
                           const float* __restrict__ gratio,
                           const float* __restrict__ infl,
                           float* __restrict__ addmap,
                           int* __restrict__ list_idx,
                           float* __restrict__ list_fu,
                           double* __restrict__ fix_delta) {
    const int k = blockIdx.x;
    const int t = threadIdx.x;
    double delta = 0.0;
    if (t < NSQ) {
        int out_idx = -1;
        float out_fu = 0.0f;
        const int ni = pos[2 * k + 0] + t / DD - RMAX;
        const int nj = pos[2 * k + 1] + t % DD - RMAX;
        if (ni >= 0 && ni < HH && nj >= 0 && nj < WW) {
            const size_t idx = (size_t)ni * WW + nj;
            const float val = atomicExch(&addmap[idx], 0.0f);
            if (val != 0.0f) {
                const float gr = *gratio;
                const float is = *infl;
                const float f = field[idx];
                const float g = signal[idx];
                const float m0 = is / (1.0f + expf(-gr));
                const float m1 = is / (1.0f + expf(-(gr + val)));
                const float fu0 = fmaf(g - f, m0, f);
                const float fu1 = fmaf(g - f, m1, f);
                out_idx = (int)idx;
                out_fu  = fu1;
                delta = (double)fu1 * (double)fu1 - (double)fu0 * (double)fu0;
            }
        }
        list_idx[k * NSQ + t] = out_idx;
        list_fu [k * NSQ + t] = out_fu;
    }
    __shared__ double sred[7];
    #pragma unroll
    for (int off = 32; off > 0; off >>= 1) delta += __shfl_down(delta, off);
    if ((t & 63) == 0) sred[t >> 6] = delta;
    __syncthreads();
    if (t == 0) {
        double d = 0.0;
        #pragma unroll
        for (int i = 0; i < 7; ++i) d += sred[i];
        fix_delta[k] = d;
    }
}

// K3: norms only. 2 float4 per stream per thread -> 4 independent loads,
// one waitcnt round. TLP from 8192 blocks (32K waves) hides latency.
__global__ void __launch_bounds__(TPB) ecli_norms(
        const float* __restrict__ field,
        const float* __restrict__ signal,
        const float* __restrict__ gratio,
        const float* __restrict__ infl,
        double* __restrict__ part_sf,
        double* __restrict__ part_su) {
    const int tid = blockIdx.x * TPB + threadIdx.x;
    const float gr = *gratio;
    const float is = *infl;
    const float m0 = is / (1.0f + expf(-gr));
    const float4* __restrict__ F = (const float4*)field;
    const float4* __restrict__ G = (const float4*)signal;

    float4 f0 = F[tid];
    float4 f1 = F[tid + NT];
    float4 g0 = G[tid];
    float4 g1 = G[tid + NT];

    float sf = 0.0f, su = 0.0f;
    float r;
    sf += f0.x*f0.x + f0.y*f0.y + f0.z*f0.z + f0.w*f0.w;
    sf += f1.x*f1.x + f1.y*f1.y + f1.z*f1.z + f1.w*f1.w;
    r = fmaf(g0.x - f0.x, m0, f0.x); su = fmaf(r, r, su);
    r = fmaf(g0.y - f0.y, m0, f0.y); su = fmaf(r, r, su);
    r = fmaf(g0.z - f0.z, m0, f0.z); su = fmaf(r, r, su);
    r = fmaf(g0.w - f0.w, m0, f0.w); su = fmaf(r, r, su);
    r = fmaf(g1.x - f1.x, m0, f1.x); su = fmaf(r, r, su);
    r = fmaf(g1.y - f1.y, m0, f1.y); su = fmaf(r, r, su);
    r = fmaf(g1.z - f1.z, m0, f1.z); su = fmaf(r, r, su);
    r = fmaf(g1.w - f1.w, m0, f1.w); su = fmaf(r, r, su);

    double a = (double)sf, b = (double)su;
    __shared__ double sred[8];
    #pragma unroll
    for (int off = 32; off > 0; off >>= 1) {
        a += __shfl_down(a, off);
        b += __shfl_down(b, off);
    }
    if ((threadIdx.x & 63) == 0) {
        sred[(threadIdx.x >> 6) * 2 + 0] = a;
        sred[(threadIdx.x >> 6) * 2 + 1] = b;
    }
    __syncthreads();
    if (threadIdx.x == 0) {
        part_sf[blockIdx.x] = sred[0] + sred[2] + sred[4] + sred[6];
        part_su[blockIdx.x] = sred[1] + sred[3] + sred[5] + sred[7];
    }
}

// K4: single-block reduce of partials + fix corrections -> scale.
__global__ void ecli_reduce(const double* __restrict__ part_sf,
                            const double* __restrict__ part_su,
                            const double* __restrict__ fix_delta,
                            float* __restrict__ scale_out) {
    const int t = threadIdx.x;     // 1024 threads
    double a = 0.0, b = 0.0;
    for (int i = t; i < NB; i += 1024) {
        a += part_sf[i];
        b += part_su[i];
    }
    if (t < KK) b += fix_delta[t];
    __shared__ double sa[16], sb[16];
    #pragma unroll
    for (int off = 32; off > 0; off >>= 1) {
        a += __shfl_down(a, off);
        b += __shfl_down(b, off);
    }
    if ((t & 63) == 0) { sa[t >> 6] = a; sb[t >> 6] = b; }
    __syncthreads();
    if (t == 0) {
        double ta = 0.0, tb = 0.0;
        #pragma unroll
        for (int i = 0; i < 16; ++i) { ta += sa[i]; tb += sb[i]; }
        *scale_out = (tb > 0.0) ? (float)sqrt(ta / tb) : 1.0f;
    }
}

// K5: out = (f + (g-f)*m0) * scale; 4 independent loads, nontemporal stores.
__global__ void __launch_bounds__(TPB) ecli_write(
        const float* __restrict__ field,
        const float* __restrict__ signal,
        const float* __restrict__ gratio,
        const float* __restrict__ infl,
        const float* __restrict__ scale_ptr,
        float* __restrict__ out) {
    const int tid = blockIdx.x * TPB + threadIdx.x;
    const float gr = *gratio;
    const float is = *infl;
    const float m0 = is / (1.0f + expf(-gr));
    const float scale = *scale_ptr;
    const float4* __restrict__ F = (const float4*)field;
    const float4* __restrict__ G = (const float4*)signal;
    vfloat4* __restrict__ O = (vfloat4*)out;

    float4 f0 = F[tid];
    float4 f1 = F[tid + NT];
    float4 g0 = G[tid];
    float4 g1 = G[tid + NT];

    vfloat4 v;
    float t_;
    t_ = fmaf(g0.x - f0.x, m0, f0.x); v.x = t_ * scale;
    t_ = fmaf(g0.y - f0.y, m0, f0.y); v.y = t_ * scale;
    t_ = fmaf(g0.z - f0.z, m0, f0.z); v.z = t_ * scale;
    t_ = fmaf(g0.w - f0.w, m0, f0.w); v.w = t_ * scale;
    __builtin_nontemporal_store(v, &O[tid]);
    t_ = fmaf(g1.x - f1.x, m0, f1.x); v.x = t_ * scale;
    t_ = fmaf(g1.y - f1.y, m0, f1.y); v.y = t_ * scale;
    t_ = fmaf(g1.z - f1.z, m0, f1.z); v.z = t_ * scale;
    t_ = fmaf(g1.w - f1.w, m0, f1.w); v.w = t_ * scale;
    __builtin_nontemporal_store(v, &O[tid + NT]);
}

// K6: apply sparse corrections, scaled.
__global__ void ecli_apply(const int* __restrict__ list_idx,
                           const float* __restrict__ list_fu,
                           const float* __restrict__ scale_ptr,
                           float* __restrict__ out) {
    const int tid = blockIdx.x * blockDim.x + threadIdx.x;
    if (tid >= MAXTOUCH) return;
    const int idx = list_idx[tid];
    if (idx < 0) return;
    out[idx] = list_fu[tid] * (*scale_ptr);
}

extern "C" void kernel_launch(void* const* d_in, const int* in_sizes, int n_in,
                              void* d_out, int out_size, void* d_ws, size_t ws_size,
                              hipStream_t stream) {
    const float* field    = (const float*)d_in[0];
    const float* signal   = (const float*)d_in[1];
    const int*   pos      = (const int*)d_in[2];
    const float* strength = (const float*)d_in[3];
    const float* infl     = (const float*)d_in[4];
    const float* gratio   = (const float*)d_in[5];
    const float* lratio   = (const float*)d_in[6];
    float* out = (float*)d_out;

    char* ws = (char*)d_ws;
    double* fix_delta = (double*)(ws + FIX_OFF);
    double* part_sf   = (double*)(ws + PSF_OFF);
    double* part_su   = (double*)(ws + PSU_OFF);
    float*  scale_ptr = (float*)(ws + SCALE_OFF);
    int*    list_idx  = (int*)(ws + LIDX_OFF);
    float*  list_fu   = (float*)(ws + LFU_OFF);

    ecli_clear  <<<KK, 448, 0, stream>>>(pos, out);
    ecli_scatter<<<KK, 448, 0, stream>>>(pos, strength, lratio, out);
    ecli_fixup  <<<KK, 448, 0, stream>>>(pos, field, signal, gratio, infl,
                                         out, list_idx, list_fu, fix_delta);
    ecli_norms  <<<NB, TPB, 0, stream>>>(field, signal, gratio, infl,
                                         part_sf, part_su);
    ecli_reduce <<<1, 1024, 0, stream>>>(part_sf, part_su, fix_delta, scale_ptr);
    ecli_write  <<<NB, TPB, 0, stream>>>(field, signal, gratio, infl,
                                         scale_ptr, out);
    ecli_apply  <<<(MAXTOUCH + 255) / 256, 256, 0, stream>>>(list_idx, list_fu,
                                                             scale_ptr, out);
}

// Round 8
// 71.197 us; speedup vs baseline: 1.0493x; 1.0336x over previous
//
#include <hip/hip_runtime.h>

#define HH 4096
#define WW 4096
#define KK 256
#define RMAX 10
#define DD 21
#define NSQ (DD * DD)              // 441
#define MAXTOUCH (KK * NSQ)        // 112896

#define NB  8192                   // blocks for dense kernels
#define TPB 256
#define NT  (NB * TPB)             // 2097152 threads; 2 float4 each
#define NWAVES (NT / 64)           // 32768
#define RB1 128                    // reduce stage-1 blocks (256 wave-pairs each)

typedef float vfloat4 __attribute__((ext_vector_type(4)));

// d_ws layout (bytes):
#define FIX_OFF   0                      // double fix_delta[KK]       (2048 B)
#define P2SF_OFF  4096                   // double part2_sf[RB1]       (1024 B)
#define P2SU_OFF  8192                   // double part2_su[RB1]       (1024 B)
#define SCALE_OFF 12288                  // float  scale
#define WSF_OFF   16384                  // float  wave_sf[NWAVES]     (131072 B)
#define WSU_OFF   (16384 + 131072)       // float  wave_su[NWAVES]     (131072 B)
#define LIDX_OFF  (WSU_OFF + 131072)     // int    list_idx[MAXTOUCH]  (451584 B)
#define LFU_OFF   (LIDX_OFF + 451584)    // float  list_fu[MAXTOUCH]

// K0: zero the 21x21 in-bounds square of every attractor in the addmap.
// addmap lives in d_out (stale output during replays; overwritten later).
__global__ void ecli_clear(const int* __restrict__ pos, float* __restrict__ addmap) {
    const int k = blockIdx.x;
    const int t = threadIdx.x;
    if (t >= NSQ) return;
    const int ni = pos[2 * k + 0] + t / DD - RMAX;
    const int nj = pos[2 * k + 1] + t % DD - RMAX;
    if (ni < 0 || ni >= HH || nj < 0 || nj >= WW) return;
    addmap[(size_t)ni * WW + nj] = 0.0f;
}

// K1: scatter-add attractor contributions (f32 atomics, uncontended).
__global__ void ecli_scatter(const int* __restrict__ pos,
                             const float* __restrict__ strength,
                             const float* __restrict__ local_ratio,
                             float* __restrict__ addmap) {
    const int k = blockIdx.x;
    const int t = threadIdx.x;
    if (t >= NSQ) return;
    const float s   = strength[k];
    const float lr  = *local_ratio;
    const float rad = floorf(5.0f * s);
    const float inv = -0.5f / (4.0f * s * s);
    const float amp = lr * s;
    const int di = t / DD - RMAX;
    const int dj = t % DD - RMAX;
    if (fabsf((float)di) > rad || fabsf((float)dj) > rad) return;
    const int ni = pos[2 * k + 0] + di;
    const int nj = pos[2 * k + 1] + dj;
    if (ni < 0 || ni >= HH || nj < 0 || nj >= WW) return;
    const float c = expf((float)(di * di + dj * dj) * inv) * amp;
    atomicAdd(&addmap[(size_t)ni * WW + nj], c);
}

// K2: claim each touched pixel once (atomicExch->0), write (idx, fu1) into
// deterministic slot, block-reduce the su-correction into fix_delta[k].
__global__ void ecli_fixup(const int* __restrict__ pos,
                           const float* __restrict__ field,
                           const float* __restrict__ signal,
                           const float* __restrict__ gratio,
                           const float* __restrict__ infl,
                           float* __restrict__ addmap,
                           int* __restrict__ list_idx,
                           float* __restrict__ list_fu,
                           double* __restrict__ fix_delta) {
    const int k = blockIdx.x;
    const int t = threadIdx.x;
    double delta = 0.0;
    if (t < NSQ) {
        int out_idx = -1;
        float out_fu = 0.0f;
        const int ni = pos[2 * k + 0] + t / DD - RMAX;
        const int nj = pos[2 * k + 1] + t % DD - RMAX;
        if (ni >= 0 && ni < HH && nj >= 0 && nj < WW) {
            const size_t idx = (size_t)ni * WW + nj;
            const float val = atomicExch(&addmap[idx], 0.0f);
            if (val != 0.0f) {
                const float gr = *gratio;
                const float is = *infl;
                const float f = field[idx];
                const float g = signal[idx];
                const float m0 = is / (1.0f + expf(-gr));
                const float m1 = is / (1.0f + expf(-(gr + val)));
                const float fu0 = fmaf(g - f, m0, f);
                const float fu1 = fmaf(g - f, m1, f);
                out_idx = (int)idx;
                out_fu  = fu1;
                delta = (double)fu1 * (double)fu1 - (double)fu0 * (double)fu0;
            }
        }
        list_idx[k * NSQ + t] = out_idx;
        list_fu [k * NSQ + t] = out_fu;
    }
    __shared__ double sred[7];
    #pragma unroll
    for (int off = 32; off > 0; off >>= 1) delta += __shfl_down(delta, off);
    if ((t & 63) == 0) sred[t >> 6] = delta;
    __syncthreads();
    if (t == 0) {
        double d = 0.0;
        #pragma unroll
        for (int i = 0; i < 7; ++i) d += sred[i];
        fix_delta[k] = d;
    }
}

// K3: norms, stripped epilogue: f32 wave-shuffle reduce ONLY.
// No doubles, no LDS, no __syncthreads, no block tail.
__global__ void __launch_bounds__(TPB) ecli_norms2(
        const float* __restrict__ field,
        const float* __restrict__ signal,
        const float* __restrict__ gratio,
        const float* __restrict__ infl,
        float* __restrict__ wave_sf,
        float* __restrict__ wave_su) {
    const int tid = blockIdx.x * TPB + threadIdx.x;
    const float gr = *gratio;
    const float is = *infl;
    const float m0 = is / (1.0f + expf(-gr));
    const float4* __restrict__ F = (const float4*)field;
    const float4* __restrict__ G = (const float4*)signal;

    float4 f0 = F[tid];
    float4 f1 = F[tid + NT];
    float4 g0 = G[tid];
    float4 g1 = G[tid + NT];

    float sf = 0.0f, su = 0.0f;
    float r;
    sf += f0.x*f0.x + f0.y*f0.y + f0.z*f0.z + f0.w*f0.w;
    sf += f1.x*f1.x + f1.y*f1.y + f1.z*f1.z + f1.w*f1.w;
    r = fmaf(g0.x - f0.x, m0, f0.x); su = fmaf(r, r, su);
    r = fmaf(g0.y - f0.y, m0, f0.y); su = fmaf(r, r, su);
    r = fmaf(g0.z - f0.z, m0, f0.z); su = fmaf(r, r, su);
    r = fmaf(g0.w - f0.w, m0, f0.w); su = fmaf(r, r, su);
    r = fmaf(g1.x - f1.x, m0, f1.x); su = fmaf(r, r, su);
    r = fmaf(g1.y - f1.y, m0, f1.y); su = fmaf(r, r, su);
    r = fmaf(g1.z - f1.z, m0, f1.z); su = fmaf(r, r, su);
    r = fmaf(g1.w - f1.w, m0, f1.w); su = fmaf(r, r, su);

    #pragma unroll
    for (int off = 32; off > 0; off >>= 1) {
        sf += __shfl_down(sf, off);
        su += __shfl_down(su, off);
    }
    if ((threadIdx.x & 63) == 0) {
        const int wid = tid >> 6;
        wave_sf[wid] = sf;
        wave_su[wid] = su;
    }
}

// K4a: reduce stage 1 — 128 blocks, each sums 256 consecutive wave-pairs.
__global__ void ecli_reduce1(const float* __restrict__ wave_sf,
                             const float* __restrict__ wave_su,
                             double* __restrict__ part2_sf,
                             double* __restrict__ part2_su) {
    const int t = threadIdx.x;   // 256
    const int base = blockIdx.x * 256;
    double a = (double)wave_sf[base + t];
    double b = (double)wave_su[base + t];
    __shared__ double sa[4], sb[4];
    #pragma unroll
    for (int off = 32; off > 0; off >>= 1) {
        a += __shfl_down(a, off);
        b += __shfl_down(b, off);
    }
    if ((t & 63) == 0) { sa[t >> 6] = a; sb[t >> 6] = b; }
    __syncthreads();
    if (t == 0) {
        part2_sf[blockIdx.x] = sa[0] + sa[1] + sa[2] + sa[3];
        part2_su[blockIdx.x] = sb[0] + sb[1] + sb[2] + sb[3];
    }
}

// K4b: reduce stage 2 — single tiny block: 128 pairs + 256 fix corrections.
__global__ void ecli_reduce2(const double* __restrict__ part2_sf,
                             const double* __restrict__ part2_su,
                             const double* __restrict__ fix_delta,
                             float* __restrict__ scale_out) {
    const int t = threadIdx.x;   // 256
    double a = 0.0, b = 0.0;
    if (t < RB1) { a = part2_sf[t]; b = part2_su[t]; }
    b += fix_delta[t];           // 256 entries
    __shared__ double sa[4], sb[4];
    #pragma unroll
    for (int off = 32; off > 0; off >>= 1) {
        a += __shfl_down(a, off);
        b += __shfl_down(b, off);
    }
    if ((t & 63) == 0) { sa[t >> 6] = a; sb[t >> 6] = b; }
    __syncthreads();
    if (t == 0) {
        const double ta = sa[0] + sa[1] + sa[2] + sa[3];
        const double tb = sb[0] + sb[1] + sb[2] + sb[3];
        *scale_out = (tb > 0.0) ? (float)sqrt(ta / tb) : 1.0f;
    }
}

// K5: out = (f + (g-f)*m0) * scale; nontemporal stores.
__global__ void __launch_bounds__(TPB) ecli_write(
        const float* __restrict__ field,
        const float* __restrict__ signal,
        const float* __restrict__ gratio,
        const float* __restrict__ infl,
        const float* __restrict__ scale_ptr,
        float* __restrict__ out) {
    const int tid = blockIdx.x * TPB + threadIdx.x;
    const float gr = *gratio;
    const float is = *infl;
    const float m0 = is / (1.0f + expf(-gr));
    const float scale = *scale_ptr;
    const float4* __restrict__ F = (const float4*)field;
    const float4* __restrict__ G = (const float4*)signal;
    vfloat4* __restrict__ O = (vfloat4*)out;

    float4 f0 = F[tid];
    float4 f1 = F[tid + NT];
    float4 g0 = G[tid];
    float4 g1 = G[tid + NT];

    vfloat4 v;
    float t_;
    t_ = fmaf(g0.x - f0.x, m0, f0.x); v.x = t_ * scale;
    t_ = fmaf(g0.y - f0.y, m0, f0.y); v.y = t_ * scale;
    t_ = fmaf(g0.z - f0.z, m0, f0.z); v.z = t_ * scale;
    t_ = fmaf(g0.w - f0.w, m0, f0.w); v.w = t_ * scale;
    __builtin_nontemporal_store(v, &O[tid]);
    t_ = fmaf(g1.x - f1.x, m0, f1.x); v.x = t_ * scale;
    t_ = fmaf(g1.y - f1.y, m0, f1.y); v.y = t_ * scale;
    t_ = fmaf(g1.z - f1.z, m0, f1.z); v.z = t_ * scale;
    t_ = fmaf(g1.w - f1.w, m0, f1.w); v.w = t_ * scale;
    __builtin_nontemporal_store(v, &O[tid + NT]);
}

// K6: apply sparse corrections, scaled.
__global__ void ecli_apply(const int* __restrict__ list_idx,
                           const float* __restrict__ list_fu,
                           const float* __restrict__ scale_ptr,
                           float* __restrict__ out) {
    const int tid = blockIdx.x * blockDim.x + threadIdx.x;
    if (tid >= MAXTOUCH) return;
    const int idx = list_idx[tid];
    if (idx < 0) return;
    out[idx] = list_fu[tid] * (*scale_ptr);
}

extern "C" void kernel_launch(void* const* d_in, const int* in_sizes, int n_in,
                              void* d_out, int out_size, void* d_ws, size_t ws_size,
                              hipStream_t stream) {
    const float* field    = (const float*)d_in[0];
    const float* signal   = (const float*)d_in[1];
    const int*   pos      = (const int*)d_in[2];
    const float* strength = (const float*)d_in[3];
    const float* infl     = (const float*)d_in[4];
    const float* gratio   = (const float*)d_in[5];
    const float* lratio   = (const float*)d_in[6];
    float* out = (float*)d_out;

    char* ws = (char*)d_ws;
    double* fix_delta = (double*)(ws + FIX_OFF);
    double* part2_sf  = (double*)(ws + P2SF_OFF);
    double* part2_su  = (double*)(ws + P2SU_OFF);
    float*  scale_ptr = (float*)(ws + SCALE_OFF);
    float*  wave_sf   = (float*)(ws + WSF_OFF);
    float*  wave_su   = (float*)(ws + WSU_OFF);
    int*    list_idx  = (int*)(ws + LIDX_OFF);
    float*  list_fu   = (float*)(ws + LFU_OFF);

    ecli_clear  <<<KK, 448, 0, stream>>>(pos, out);
    ecli_scatter<<<KK, 448, 0, stream>>>(pos, strength, lratio, out);
    ecli_fixup  <<<KK, 448, 0, stream>>>(pos, field, signal, gratio, infl,
                                         out, list_idx, list_fu, fix_delta);
    ecli_norms2 <<<NB, TPB, 0, stream>>>(field, signal, gratio, infl,
                                         wave_sf, wave_su);
    ecli_reduce1<<<RB1, 256, 0, stream>>>(wave_sf, wave_su, part2_sf, part2_su);
    ecli_reduce2<<<1, 256, 0, stream>>>(part2_sf, part2_su, fix_delta, scale_ptr);
    ecli_write  <<<NB, TPB, 0, stream>>>(field, signal, gratio, infl,
                                         scale_ptr, out);
    ecli_apply  <<<(MAXTOUCH + 255) / 256, 256, 0, stream>>>(list_idx, list_fu,
                                                             scale_ptr, out);
}